// Round 1
// baseline (1011.655 us; speedup 1.0000x reference)
//
#include <hip/hip_runtime.h>
#include <math.h>

#define C_CH 54
#define CP   56      // padded candidate row (16B-aligned rows, zero pad)
#define NT   20
#define NM   6
#define NK   120     // NM * NT

// ---------------- prep: candidates, norms, t grid, lib means ----------------
__global__ __launch_bounds__(256) void hadar_prep(
    const float* __restrict__ s_sky, const float* __restrict__ s_ground,
    const float* __restrict__ library, const float* __restrict__ wg,
    float* __restrict__ cand, float* __restrict__ candsq,
    float* __restrict__ tcand, float* __restrict__ libmean)
{
    __shared__ float xamb[C_CH];
    __shared__ float tc[NT];
    const int tid = threadIdx.x;
    if (tid < NT) {
        float t = 250.0f + (float)tid * (100.0f / 19.0f);
        tc[tid] = t;
        tcand[tid] = t;
    }
    if (tid < C_CH) xamb[tid] = 0.5f * s_sky[tid] + 0.5f * s_ground[tid];
    __syncthreads();

    const float c1 = 1.191042e-8f, c2 = 1.4387752f;
    for (int idx = tid; idx < NK * CP; idx += 256) {
        const int k = idx / CP, c = idx % CP;
        float v = 0.0f;
        if (c < C_CH) {
            const int m = k / NT, t = k % NT;
            const float nu = wg[c];
            const float B = c1 * nu * nu * nu / expm1f(c2 * nu / tc[t]);
            const float e = library[m * C_CH + c];
            v = e * B + (1.0f - e) * xamb[c];
        }
        cand[idx] = v;
    }
    __syncthreads();

    if (tid < NK) {
        float s = 0.0f;
        for (int c = 0; c < C_CH; ++c) { float v = cand[tid * CP + c]; s += v * v; }
        candsq[tid] = s;
    }
    if (tid < NM) {
        float s = 0.0f;
        for (int c = 0; c < C_CH; ++c) s += library[tid * C_CH + c];
        libmean[tid] = s / (float)C_CH;
    }
}

// ---------------- main: per-pixel argmin over 120 candidates ----------------
__global__ __launch_bounds__(256) void hadar_main(
    const float* __restrict__ s_obs,
    const float* __restrict__ library,
    const float* __restrict__ cand, const float* __restrict__ candsq,
    const float* __restrict__ tcand, const float* __restrict__ libmean,
    float* __restrict__ out, float* __restrict__ partials, int N)
{
    const int n = blockIdx.x * 256 + threadIdx.x;

    float best_loss = 0.0f;
    if (n < N) {
        float row[CP];
        const float2* rp = (const float2*)(s_obs + (size_t)n * C_CH);
        #pragma unroll
        for (int i = 0; i < C_CH / 2; ++i) {
            float2 v = rp[i];
            row[2 * i] = v.x; row[2 * i + 1] = v.y;
        }
        row[54] = 0.0f; row[55] = 0.0f;

        float ssq = 0.0f;
        #pragma unroll
        for (int c = 0; c < C_CH; ++c) ssq += row[c] * row[c];

        best_loss = 3.4e38f;
        int bestk = 0;
        #pragma unroll 2
        for (int k = 0; k < NK; ++k) {
            const float* ck = cand + k * CP;
            float a0 = 0.f, a1 = 0.f, a2 = 0.f, a3 = 0.f;
            #pragma unroll
            for (int c = 0; c < CP; c += 4) {
                a0 += row[c + 0] * ck[c + 0];
                a1 += row[c + 1] * ck[c + 1];
                a2 += row[c + 2] * ck[c + 2];
                a3 += row[c + 3] * ck[c + 3];
            }
            const float dot = (a0 + a1) + (a2 + a3);
            const float loss = (ssq - 2.0f * dot) + candsq[k];
            if (loss < best_loss) { best_loss = loss; bestk = k; }
        }

        const size_t NN = (size_t)N;
        const size_t NC = (size_t)C_CH * NN;
        const int m = bestk / NT, t = bestk % NT;

        out[n] = tcand[t];                       // best_t
        out[NN + NC + n] = 0.5f;                 // best_v
        out[2 * NN + NC + n] = 0.0f;             // beta
        out[3 * NN + NC + n] = libmean[m];       // texture

        // best_e = library[m]
        float2* bep = (float2*)(out + NN + (size_t)n * C_CH);
        const float2* lp = (const float2*)(library + m * C_CH);
        #pragma unroll
        for (int i = 0; i < C_CH / 2; ++i) bep[i] = lp[i];

        // s_recon = cand[bestk]
        float2* srp = (float2*)(out + 4 * NN + NC + (size_t)n * C_CH);
        const float2* cp2 = (const float2*)(cand + bestk * CP);
        #pragma unroll
        for (int i = 0; i < C_CH / 2; ++i) srp[i] = cp2[i];
    }

    // deterministic block reduction of best_loss
    __shared__ float red[256];
    red[threadIdx.x] = (n < N) ? best_loss : 0.0f;
    __syncthreads();
    #pragma unroll
    for (int s = 128; s > 0; s >>= 1) {
        if (threadIdx.x < s) red[threadIdx.x] += red[threadIdx.x + s];
        __syncthreads();
    }
    if (threadIdx.x == 0) partials[blockIdx.x] = red[0];
}

// ---------------- final reduce: objective = mean(best_loss) ----------------
__global__ __launch_bounds__(256) void hadar_reduce(
    const float* __restrict__ partials, int nb, float* __restrict__ obj_out, float invN)
{
    __shared__ float red[256];
    float s = 0.0f;
    for (int i = threadIdx.x; i < nb; i += 256) s += partials[i];
    red[threadIdx.x] = s;
    __syncthreads();
    #pragma unroll
    for (int st = 128; st > 0; st >>= 1) {
        if (threadIdx.x < st) red[threadIdx.x] += red[threadIdx.x + st];
        __syncthreads();
    }
    if (threadIdx.x == 0) *obj_out = red[0] * invN;
}

extern "C" void kernel_launch(void* const* d_in, const int* in_sizes, int n_in,
                              void* d_out, int out_size, void* d_ws, size_t ws_size,
                              hipStream_t stream)
{
    const float* s_obs    = (const float*)d_in[0];
    const float* s_sky    = (const float*)d_in[1];
    const float* s_ground = (const float*)d_in[2];
    const float* library  = (const float*)d_in[3];
    const float* wg       = (const float*)d_in[4];
    float* out = (float*)d_out;

    const int N  = in_sizes[0] / C_CH;
    const int nb = (N + 255) / 256;

    float* ws      = (float*)d_ws;
    float* cand    = ws;                 // NK*CP = 6720
    float* candsq  = ws + NK * CP;       // 120
    float* tcand   = candsq + NK;        // 20
    float* libmean = tcand + NT;         // 6
    float* partials = ws + 8192;         // nb floats

    hadar_prep<<<1, 256, 0, stream>>>(s_sky, s_ground, library, wg,
                                      cand, candsq, tcand, libmean);
    hadar_main<<<nb, 256, 0, stream>>>(s_obs, library, cand, candsq, tcand, libmean,
                                       out, partials, N);

    const size_t NN = (size_t)N;
    float* obj_out = out + 4 * NN + 2 * (size_t)C_CH * NN;
    hadar_reduce<<<1, 256, 0, stream>>>(partials, nb, obj_out, 1.0f / (float)N);
}

// Round 2
// 914.746 us; speedup vs baseline: 1.1059x; 1.1059x over previous
//
#include <hip/hip_runtime.h>
#include <math.h>

#define C_CH 54
#define CP   56      // padded candidate row (16B-aligned rows, zero pad)
#define NT   20
#define NM   6
#define NK   120     // NM * NT
#define PIX  3       // pixels per thread
#define BLK  256
#define PPB  (BLK * PIX)   // 768 pixels per block

// Fused: per-block candidate-table build in LDS + per-pixel argmin.
// All per-pixel arithmetic is bit-identical to the round-1 kernel.
__global__ __launch_bounds__(BLK, 2) void hadar_main(
    const float* __restrict__ s_obs,
    const float* __restrict__ s_sky, const float* __restrict__ s_ground,
    const float* __restrict__ library, const float* __restrict__ wg,
    float* __restrict__ out, float* __restrict__ partials, int N)
{
    __shared__ __align__(16) float cand[NK * CP];   // 26880 B
    __shared__ float candsq[NK];
    __shared__ float tc[NT];
    __shared__ float xamb[C_CH];
    __shared__ float libl[NM * C_CH];
    __shared__ float libmean[NM];

    const int tid = threadIdx.x;
    const long long base = (long long)blockIdx.x * PPB + tid;

    // ---- issue pixel-row loads early (overlap global latency with prep) ----
    float row[PIX][CP];
    bool  valid[PIX];
    #pragma unroll
    for (int p = 0; p < PIX; ++p) {
        const long long np = base + (long long)p * BLK;
        valid[p] = (np < N);
        row[p][54] = 0.0f; row[p][55] = 0.0f;
        if (valid[p]) {
            const float2* rp = (const float2*)(s_obs + np * C_CH);
            #pragma unroll
            for (int i = 0; i < C_CH / 2; ++i) {
                float2 v = rp[i];
                row[p][2 * i] = v.x; row[p][2 * i + 1] = v.y;
            }
        } else {
            #pragma unroll
            for (int c = 0; c < C_CH; ++c) row[p][c] = 0.0f;
        }
    }

    // ---- per-block prep: candidate table into LDS (identical formulas) ----
    if (tid < NT) tc[tid] = 250.0f + (float)tid * (100.0f / 19.0f);
    if (tid < C_CH) xamb[tid] = 0.5f * s_sky[tid] + 0.5f * s_ground[tid];
    for (int i = tid; i < NM * C_CH; i += BLK) libl[i] = library[i];
    __syncthreads();

    const float c1 = 1.191042e-8f, c2 = 1.4387752f;
    for (int idx = tid; idx < NK * CP; idx += BLK) {
        const int k = idx / CP, c = idx - k * CP;
        float v = 0.0f;
        if (c < C_CH) {
            const int m = k / NT, t = k - m * NT;
            const float nu = wg[c];
            const float B = c1 * nu * nu * nu / expm1f(c2 * nu / tc[t]);
            const float e = libl[m * C_CH + c];
            v = e * B + (1.0f - e) * xamb[c];
        }
        cand[idx] = v;
    }
    __syncthreads();

    if (tid < NK) {
        float s = 0.0f;
        for (int c = 0; c < C_CH; ++c) { float v = cand[tid * CP + c]; s += v * v; }
        candsq[tid] = s;
    }
    if (tid < NM) {
        float s = 0.0f;
        for (int c = 0; c < C_CH; ++c) s += libl[tid * C_CH + c];
        libmean[tid] = s / (float)C_CH;
    }
    __syncthreads();

    // ---- per-pixel ssq (same sequential order as round 1) ----
    float ssq[PIX];
    #pragma unroll
    for (int p = 0; p < PIX; ++p) {
        float s = 0.0f;
        #pragma unroll
        for (int c = 0; c < C_CH; ++c) s += row[p][c] * row[p][c];
        ssq[p] = s;
    }

    // ---- argmin over 120 candidates; cand broadcast from LDS ----
    float best_loss[PIX];
    int   bestk[PIX];
    #pragma unroll
    for (int p = 0; p < PIX; ++p) { best_loss[p] = 3.4e38f; bestk[p] = 0; }

    #pragma unroll 2
    for (int k = 0; k < NK; ++k) {
        const float* ck = cand + k * CP;
        float a[PIX][4];
        #pragma unroll
        for (int p = 0; p < PIX; ++p)
            { a[p][0] = 0.f; a[p][1] = 0.f; a[p][2] = 0.f; a[p][3] = 0.f; }
        #pragma unroll
        for (int c = 0; c < CP; c += 4) {
            const float4 q = *(const float4*)(ck + c);
            #pragma unroll
            for (int p = 0; p < PIX; ++p) {
                a[p][0] += row[p][c + 0] * q.x;
                a[p][1] += row[p][c + 1] * q.y;
                a[p][2] += row[p][c + 2] * q.z;
                a[p][3] += row[p][c + 3] * q.w;
            }
        }
        #pragma unroll
        for (int p = 0; p < PIX; ++p) {
            const float dot = (a[p][0] + a[p][1]) + (a[p][2] + a[p][3]);
            const float loss = (ssq[p] - 2.0f * dot) + candsq[k];
            if (loss < best_loss[p]) { best_loss[p] = loss; bestk[p] = k; }
        }
    }

    // ---- outputs ----
    const size_t NN = (size_t)N;
    const size_t NC = (size_t)C_CH * NN;
    float lsum = 0.0f;
    #pragma unroll
    for (int p = 0; p < PIX; ++p) {
        const long long np = base + (long long)p * BLK;
        if (!valid[p]) continue;
        lsum += best_loss[p];
        const int m = bestk[p] / NT, t = bestk[p] - m * NT;

        out[np] = tc[t];                         // best_t
        out[NN + NC + np] = 0.5f;                // best_v
        out[2 * NN + NC + np] = 0.0f;            // beta
        out[3 * NN + NC + np] = libmean[m];      // texture

        float2* bep = (float2*)(out + NN + (size_t)np * C_CH);
        const float2* lp = (const float2*)(libl + m * C_CH);
        #pragma unroll
        for (int i = 0; i < C_CH / 2; ++i) bep[i] = lp[i];

        float2* srp = (float2*)(out + 4 * NN + NC + (size_t)np * C_CH);
        const float2* cp2 = (const float2*)(cand + bestk[p] * CP);
        #pragma unroll
        for (int i = 0; i < C_CH / 2; ++i) srp[i] = cp2[i];
    }

    // ---- deterministic block reduction of best_loss sum ----
    __shared__ float red[BLK];
    red[tid] = lsum;
    __syncthreads();
    #pragma unroll
    for (int s = BLK / 2; s > 0; s >>= 1) {
        if (tid < s) red[tid] += red[tid + s];
        __syncthreads();
    }
    if (tid == 0) partials[blockIdx.x] = red[0];
}

// ---------------- final reduce: objective = mean(best_loss) ----------------
__global__ __launch_bounds__(256) void hadar_reduce(
    const float* __restrict__ partials, int nb, float* __restrict__ obj_out, float invN)
{
    __shared__ float red[256];
    float s = 0.0f;
    for (int i = threadIdx.x; i < nb; i += 256) s += partials[i];
    red[threadIdx.x] = s;
    __syncthreads();
    #pragma unroll
    for (int st = 128; st > 0; st >>= 1) {
        if (threadIdx.x < st) red[threadIdx.x] += red[threadIdx.x + st];
        __syncthreads();
    }
    if (threadIdx.x == 0) *obj_out = red[0] * invN;
}

extern "C" void kernel_launch(void* const* d_in, const int* in_sizes, int n_in,
                              void* d_out, int out_size, void* d_ws, size_t ws_size,
                              hipStream_t stream)
{
    const float* s_obs    = (const float*)d_in[0];
    const float* s_sky    = (const float*)d_in[1];
    const float* s_ground = (const float*)d_in[2];
    const float* library  = (const float*)d_in[3];
    const float* wg       = (const float*)d_in[4];
    float* out = (float*)d_out;

    const int N  = in_sizes[0] / C_CH;
    const int nb = (N + PPB - 1) / PPB;

    float* partials = (float*)d_ws;

    hadar_main<<<nb, BLK, 0, stream>>>(s_obs, s_sky, s_ground, library, wg,
                                       out, partials, N);

    const size_t NN = (size_t)N;
    float* obj_out = out + 4 * NN + 2 * (size_t)C_CH * NN;
    hadar_reduce<<<1, 256, 0, stream>>>(partials, nb, obj_out, 1.0f / (float)N);
}

// Round 3
// 835.873 us; speedup vs baseline: 1.2103x; 1.0944x over previous
//
#include <hip/hip_runtime.h>
#include <math.h>

#define C_CH 54
#define CP   64      // candidate row stride: [0..53]=cand, 54=candsq, 55=tcand, 56=libmean
#define NT   20
#define NM   6
#define NK   120     // NM * NT
#define PIX  2       // pixels per thread
#define BLK  256
#define PPB  (BLK * PIX)   // 512 pixels per block

typedef float sf16 __attribute__((ext_vector_type(16)));
typedef float sf8  __attribute__((ext_vector_type(8)));

// ---------------- prep: candidate table (CP=64 rows) into workspace ----------------
__global__ __launch_bounds__(256) void hadar_prep(
    const float* __restrict__ s_sky, const float* __restrict__ s_ground,
    const float* __restrict__ library, const float* __restrict__ wg,
    float* __restrict__ cand)
{
    __shared__ float xamb[C_CH];
    __shared__ float tc[NT];
    __shared__ float lm[NM];
    const int tid = threadIdx.x;
    if (tid < NT) tc[tid] = 250.0f + (float)tid * (100.0f / 19.0f);
    if (tid < C_CH) xamb[tid] = 0.5f * s_sky[tid] + 0.5f * s_ground[tid];
    if (tid < NM) {
        float s = 0.0f;
        for (int c = 0; c < C_CH; ++c) s += library[tid * C_CH + c];
        lm[tid] = s / (float)C_CH;
    }
    __syncthreads();

    const float c1 = 1.191042e-8f, c2 = 1.4387752f;
    for (int idx = tid; idx < NK * CP; idx += 256) {
        const int k = idx >> 6, c = idx & 63;
        float v = 0.0f;
        if (c < C_CH) {
            const int m = k / NT, t = k - m * NT;
            const float nu = wg[c];
            const float B = c1 * nu * nu * nu / expm1f(c2 * nu / tc[t]);
            const float e = library[m * C_CH + c];
            v = e * B + (1.0f - e) * xamb[c];
        }
        cand[idx] = v;
    }
    __syncthreads();

    if (tid < NK) {
        float s = 0.0f;
        for (int c = 0; c < C_CH; ++c) { float v = cand[tid * CP + c]; s += v * v; }
        const int m = tid / NT, t = tid - m * NT;
        cand[tid * CP + 54] = s;        // candsq
        cand[tid * CP + 55] = tc[t];    // best_t value for this k
        cand[tid * CP + 56] = lm[m];    // texture value for this k
    }
}

// element c of the current candidate row held in SGPRs (c is compile-time after unroll)
#define CE(c) ((c) < 16 ? q0[(c)] : (c) < 32 ? q1[(c)-16] : (c) < 48 ? q2[(c)-32] : q3[(c)-48])

// ---------------- main: per-pixel argmin, candidate rows via scalar loads ----------------
__global__ __launch_bounds__(BLK, 3) void hadar_main(
    const float* __restrict__ s_obs,
    const float* __restrict__ library,
    const float* __restrict__ cand,
    float* __restrict__ out, float* __restrict__ partials, int N)
{
    const int tid = threadIdx.x;
    const long long n0 = (long long)blockIdx.x * PPB + tid;
    const long long n1 = n0 + BLK;
    const bool v0 = (n0 < N), v1 = (n1 < N);

    // pixel rows in VGPRs (2 * 54 floats)
    float row0[C_CH], row1[C_CH];
    if (v0) {
        const float2* rp = (const float2*)(s_obs + n0 * C_CH);
        #pragma unroll
        for (int i = 0; i < C_CH / 2; ++i) {
            float2 w = rp[i];
            row0[2 * i] = w.x; row0[2 * i + 1] = w.y;
        }
    } else {
        #pragma unroll
        for (int c = 0; c < C_CH; ++c) row0[c] = 0.0f;
    }
    if (v1) {
        const float2* rp = (const float2*)(s_obs + n1 * C_CH);
        #pragma unroll
        for (int i = 0; i < C_CH / 2; ++i) {
            float2 w = rp[i];
            row1[2 * i] = w.x; row1[2 * i + 1] = w.y;
        }
    } else {
        #pragma unroll
        for (int c = 0; c < C_CH; ++c) row1[c] = 0.0f;
    }

    // ssq, same sequential order as round 1
    float ssq0 = 0.0f, ssq1 = 0.0f;
    #pragma unroll
    for (int c = 0; c < C_CH; ++c) ssq0 += row0[c] * row0[c];
    #pragma unroll
    for (int c = 0; c < C_CH; ++c) ssq1 += row1[c] * row1[c];

    float bl0 = 3.4e38f, bl1 = 3.4e38f;
    int bk0 = 0, bk1 = 0;

    const float* pk = cand;
    for (int k = 0; k < NK; ++k, pk += CP) {
        sf16 q0, q1, q2;
        sf8  q3;
        asm volatile("s_load_dwordx16 %0, %1, 0x0"  : "=s"(q0) : "s"(pk));
        asm volatile("s_load_dwordx16 %0, %1, 0x40" : "=s"(q1) : "s"(pk));
        asm volatile("s_load_dwordx16 %0, %1, 0x80" : "=s"(q2) : "s"(pk));
        asm volatile("s_load_dwordx8  %0, %1, 0xc0" : "=s"(q3) : "s"(pk));
        // tie the wait to the loaded values so consumers can't be hoisted above it
        asm volatile("s_waitcnt lgkmcnt(0)" : "+s"(q0), "+s"(q1), "+s"(q2), "+s"(q3));

        float a0[4] = {0.f, 0.f, 0.f, 0.f};
        float a1[4] = {0.f, 0.f, 0.f, 0.f};
        #pragma unroll
        for (int c = 0; c < C_CH; ++c) {
            const float cv = CE(c);
            a0[c & 3] += row0[c] * cv;
            a1[c & 3] += row1[c] * cv;
        }
        const float sq = q3[6];   // slot 54 = candsq
        const float d0 = (a0[0] + a0[1]) + (a0[2] + a0[3]);
        const float d1 = (a1[0] + a1[1]) + (a1[2] + a1[3]);
        const float l0 = (ssq0 - 2.0f * d0) + sq;
        const float l1 = (ssq1 - 2.0f * d1) + sq;
        if (l0 < bl0) { bl0 = l0; bk0 = k; }
        if (l1 < bl1) { bl1 = l1; bk1 = k; }
    }

    // ---- outputs ----
    const size_t NN = (size_t)N;
    const size_t NC = (size_t)C_CH * NN;
    float lsum = 0.0f;

    #pragma unroll
    for (int p = 0; p < PIX; ++p) {
        const long long np = (p == 0) ? n0 : n1;
        const bool vp = (p == 0) ? v0 : v1;
        const int bk = (p == 0) ? bk0 : bk1;
        const float bl = (p == 0) ? bl0 : bl1;
        if (!vp) continue;
        lsum += bl;
        const int m = bk / NT;
        const float* crow = cand + (size_t)bk * CP;

        out[np] = crow[55];                      // best_t
        out[NN + NC + np] = 0.5f;                // best_v
        out[2 * NN + NC + np] = 0.0f;            // beta
        out[3 * NN + NC + np] = crow[56];        // texture

        // best_e = library[m]
        float2* bep = (float2*)(out + NN + (size_t)np * C_CH);
        const float2* lp = (const float2*)(library + m * C_CH);
        #pragma unroll
        for (int i = 0; i < C_CH / 2; ++i) bep[i] = lp[i];

        // s_recon = cand[bk]
        float2* srp = (float2*)(out + 4 * NN + NC + (size_t)np * C_CH);
        const float2* cp2 = (const float2*)crow;
        #pragma unroll
        for (int i = 0; i < C_CH / 2; ++i) srp[i] = cp2[i];
    }

    // ---- deterministic block reduction of best_loss sum ----
    __shared__ float red[BLK];
    red[tid] = lsum;
    __syncthreads();
    #pragma unroll
    for (int s = BLK / 2; s > 0; s >>= 1) {
        if (tid < s) red[tid] += red[tid + s];
        __syncthreads();
    }
    if (tid == 0) partials[blockIdx.x] = red[0];
}

// ---------------- final reduce: objective = mean(best_loss) ----------------
__global__ __launch_bounds__(256) void hadar_reduce(
    const float* __restrict__ partials, int nb, float* __restrict__ obj_out, float invN)
{
    __shared__ float red[256];
    float s = 0.0f;
    for (int i = threadIdx.x; i < nb; i += 256) s += partials[i];
    red[threadIdx.x] = s;
    __syncthreads();
    #pragma unroll
    for (int st = 128; st > 0; st >>= 1) {
        if (threadIdx.x < st) red[threadIdx.x] += red[threadIdx.x + st];
        __syncthreads();
    }
    if (threadIdx.x == 0) *obj_out = red[0] * invN;
}

extern "C" void kernel_launch(void* const* d_in, const int* in_sizes, int n_in,
                              void* d_out, int out_size, void* d_ws, size_t ws_size,
                              hipStream_t stream)
{
    const float* s_obs    = (const float*)d_in[0];
    const float* s_sky    = (const float*)d_in[1];
    const float* s_ground = (const float*)d_in[2];
    const float* library  = (const float*)d_in[3];
    const float* wg       = (const float*)d_in[4];
    float* out = (float*)d_out;

    const int N  = in_sizes[0] / C_CH;
    const int nb = (N + PPB - 1) / PPB;

    float* ws       = (float*)d_ws;
    float* cand     = ws;              // NK*CP = 7680 floats
    float* partials = ws + 8192;       // nb floats

    hadar_prep<<<1, 256, 0, stream>>>(s_sky, s_ground, library, wg, cand);
    hadar_main<<<nb, BLK, 0, stream>>>(s_obs, library, cand, out, partials, N);

    const size_t NN = (size_t)N;
    float* obj_out = out + 4 * NN + 2 * (size_t)C_CH * NN;
    hadar_reduce<<<1, 256, 0, stream>>>(partials, nb, obj_out, 1.0f / (float)N);
}

// Round 4
// 831.348 us; speedup vs baseline: 1.2169x; 1.0054x over previous
//
#include <hip/hip_runtime.h>
#include <math.h>

#define C_CH 54
#define CP   64      // candidate row stride: [0..53]=cand, 54=candsq, 55=tcand, 56=libmean
#define NT   20
#define NM   6
#define NK   120     // NM * NT
#define PIX  2       // pixels per thread
#define BLK  256
#define PPB  (BLK * PIX)   // 512 pixels per block

typedef float sf16 __attribute__((ext_vector_type(16)));
typedef float sf8  __attribute__((ext_vector_type(8)));

// ---------------- prep: candidate table (CP=64 rows) into workspace ----------------
__global__ __launch_bounds__(256) void hadar_prep(
    const float* __restrict__ s_sky, const float* __restrict__ s_ground,
    const float* __restrict__ library, const float* __restrict__ wg,
    float* __restrict__ cand)
{
    __shared__ float xamb[C_CH];
    __shared__ float tc[NT];
    __shared__ float lm[NM];
    const int tid = threadIdx.x;
    if (tid < NT) tc[tid] = 250.0f + (float)tid * (100.0f / 19.0f);
    if (tid < C_CH) xamb[tid] = 0.5f * s_sky[tid] + 0.5f * s_ground[tid];
    if (tid < NM) {
        float s = 0.0f;
        for (int c = 0; c < C_CH; ++c) s += library[tid * C_CH + c];
        lm[tid] = s / (float)C_CH;
    }
    __syncthreads();

    const float c1 = 1.191042e-8f, c2 = 1.4387752f;
    for (int idx = tid; idx < NK * CP; idx += 256) {
        const int k = idx >> 6, c = idx & 63;
        float v = 0.0f;
        if (c < C_CH) {
            const int m = k / NT, t = k - m * NT;
            const float nu = wg[c];
            const float B = c1 * nu * nu * nu / expm1f(c2 * nu / tc[t]);
            const float e = library[m * C_CH + c];
            v = e * B + (1.0f - e) * xamb[c];
        }
        cand[idx] = v;
    }
    __syncthreads();

    if (tid < NK) {
        float s = 0.0f;
        for (int c = 0; c < C_CH; ++c) { float v = cand[tid * CP + c]; s += v * v; }
        const int m = tid / NT, t = tid - m * NT;
        cand[tid * CP + 54] = s;        // candsq
        cand[tid * CP + 55] = tc[t];    // best_t value for this k
        cand[tid * CP + 56] = lm[m];    // texture value for this k
    }
}

// element c of the current candidate row held in SGPRs (c is compile-time after unroll)
#define CE(c) ((c) < 16 ? q0[(c)] : (c) < 32 ? q1[(c)-16] : (c) < 48 ? q2[(c)-32] : q3[(c)-48])

// ---------------- main: per-pixel argmin, candidate rows via scalar loads ----------------
// amdgpu_waves_per_eu(3,3): pin exactly 3 waves/SIMD -> VGPR budget 170.
// Kernel needs ~140 VGPRs (108 row floats + accums + addresses); with the
// round-3 launch_bounds(256,3) the allocator targeted 6 waves (85 VGPRs) and
// SPILLED the rows to scratch -> L1-bound. Pinning (3,3) forbids that.
__attribute__((amdgpu_waves_per_eu(3, 3)))
__global__ __launch_bounds__(BLK) void hadar_main(
    const float* __restrict__ s_obs,
    const float* __restrict__ library,
    const float* __restrict__ cand,
    float* __restrict__ out, float* __restrict__ partials, int N)
{
    const int tid = threadIdx.x;
    const long long n0 = (long long)blockIdx.x * PPB + tid;
    const long long n1 = n0 + BLK;
    const bool v0 = (n0 < N), v1 = (n1 < N);

    // pixel rows in VGPRs (2 * 54 floats)
    float row0[C_CH], row1[C_CH];
    if (v0) {
        const float2* rp = (const float2*)(s_obs + n0 * C_CH);
        #pragma unroll
        for (int i = 0; i < C_CH / 2; ++i) {
            float2 w = rp[i];
            row0[2 * i] = w.x; row0[2 * i + 1] = w.y;
        }
    } else {
        #pragma unroll
        for (int c = 0; c < C_CH; ++c) row0[c] = 0.0f;
    }
    if (v1) {
        const float2* rp = (const float2*)(s_obs + n1 * C_CH);
        #pragma unroll
        for (int i = 0; i < C_CH / 2; ++i) {
            float2 w = rp[i];
            row1[2 * i] = w.x; row1[2 * i + 1] = w.y;
        }
    } else {
        #pragma unroll
        for (int c = 0; c < C_CH; ++c) row1[c] = 0.0f;
    }

    // ssq, same sequential order as round 1
    float ssq0 = 0.0f, ssq1 = 0.0f;
    #pragma unroll
    for (int c = 0; c < C_CH; ++c) ssq0 += row0[c] * row0[c];
    #pragma unroll
    for (int c = 0; c < C_CH; ++c) ssq1 += row1[c] * row1[c];

    float bl0 = 3.4e38f, bl1 = 3.4e38f;
    int bk0 = 0, bk1 = 0;

    const float* pk = cand;
    #pragma unroll 1
    for (int k = 0; k < NK; ++k, pk += CP) {
        sf16 q0, q1, q2;
        sf8  q3;
        asm volatile("s_load_dwordx16 %0, %1, 0x0"  : "=s"(q0) : "s"(pk));
        asm volatile("s_load_dwordx16 %0, %1, 0x40" : "=s"(q1) : "s"(pk));
        asm volatile("s_load_dwordx16 %0, %1, 0x80" : "=s"(q2) : "s"(pk));
        asm volatile("s_load_dwordx8  %0, %1, 0xc0" : "=s"(q3) : "s"(pk));
        // tie the wait to the loaded values so consumers can't be hoisted above it
        asm volatile("s_waitcnt lgkmcnt(0)" : "+s"(q0), "+s"(q1), "+s"(q2), "+s"(q3));

        float a0[4] = {0.f, 0.f, 0.f, 0.f};
        float a1[4] = {0.f, 0.f, 0.f, 0.f};
        #pragma unroll
        for (int c = 0; c < C_CH; ++c) {
            const float cv = CE(c);
            a0[c & 3] += row0[c] * cv;
            a1[c & 3] += row1[c] * cv;
        }
        const float sq = q3[6];   // slot 54 = candsq
        const float d0 = (a0[0] + a0[1]) + (a0[2] + a0[3]);
        const float d1 = (a1[0] + a1[1]) + (a1[2] + a1[3]);
        const float l0 = (ssq0 - 2.0f * d0) + sq;
        const float l1 = (ssq1 - 2.0f * d1) + sq;
        if (l0 < bl0) { bl0 = l0; bk0 = k; }
        if (l1 < bl1) { bl1 = l1; bk1 = k; }
    }

    // ---- outputs ----
    const size_t NN = (size_t)N;
    const size_t NC = (size_t)C_CH * NN;
    float lsum = 0.0f;

    #pragma unroll
    for (int p = 0; p < PIX; ++p) {
        const long long np = (p == 0) ? n0 : n1;
        const bool vp = (p == 0) ? v0 : v1;
        const int bk = (p == 0) ? bk0 : bk1;
        const float bl = (p == 0) ? bl0 : bl1;
        if (!vp) continue;
        lsum += bl;
        const int m = bk / NT;
        const float* crow = cand + (size_t)bk * CP;

        out[np] = crow[55];                      // best_t
        out[NN + NC + np] = 0.5f;                // best_v
        out[2 * NN + NC + np] = 0.0f;            // beta
        out[3 * NN + NC + np] = crow[56];        // texture

        // best_e = library[m]
        float2* bep = (float2*)(out + NN + (size_t)np * C_CH);
        const float2* lp = (const float2*)(library + m * C_CH);
        #pragma unroll
        for (int i = 0; i < C_CH / 2; ++i) bep[i] = lp[i];

        // s_recon = cand[bk]
        float2* srp = (float2*)(out + 4 * NN + NC + (size_t)np * C_CH);
        const float2* cp2 = (const float2*)crow;
        #pragma unroll
        for (int i = 0; i < C_CH / 2; ++i) srp[i] = cp2[i];
    }

    // ---- deterministic block reduction of best_loss sum ----
    __shared__ float red[BLK];
    red[tid] = lsum;
    __syncthreads();
    #pragma unroll
    for (int s = BLK / 2; s > 0; s >>= 1) {
        if (tid < s) red[tid] += red[tid + s];
        __syncthreads();
    }
    if (tid == 0) partials[blockIdx.x] = red[0];
}

// ---------------- final reduce: objective = mean(best_loss) ----------------
__global__ __launch_bounds__(256) void hadar_reduce(
    const float* __restrict__ partials, int nb, float* __restrict__ obj_out, float invN)
{
    __shared__ float red[256];
    float s = 0.0f;
    for (int i = threadIdx.x; i < nb; i += 256) s += partials[i];
    red[threadIdx.x] = s;
    __syncthreads();
    #pragma unroll
    for (int st = 128; st > 0; st >>= 1) {
        if (threadIdx.x < st) red[threadIdx.x] += red[threadIdx.x + st];
        __syncthreads();
    }
    if (threadIdx.x == 0) *obj_out = red[0] * invN;
}

extern "C" void kernel_launch(void* const* d_in, const int* in_sizes, int n_in,
                              void* d_out, int out_size, void* d_ws, size_t ws_size,
                              hipStream_t stream)
{
    const float* s_obs    = (const float*)d_in[0];
    const float* s_sky    = (const float*)d_in[1];
    const float* s_ground = (const float*)d_in[2];
    const float* library  = (const float*)d_in[3];
    const float* wg       = (const float*)d_in[4];
    float* out = (float*)d_out;

    const int N  = in_sizes[0] / C_CH;
    const int nb = (N + PPB - 1) / PPB;

    float* ws       = (float*)d_ws;
    float* cand     = ws;              // NK*CP = 7680 floats
    float* partials = ws + 8192;       // nb floats

    hadar_prep<<<1, 256, 0, stream>>>(s_sky, s_ground, library, wg, cand);
    hadar_main<<<nb, BLK, 0, stream>>>(s_obs, library, cand, out, partials, N);

    const size_t NN = (size_t)N;
    float* obj_out = out + 4 * NN + 2 * (size_t)C_CH * NN;
    hadar_reduce<<<1, 256, 0, stream>>>(partials, nb, obj_out, 1.0f / (float)N);
}